// Round 1
// baseline (1663.473 us; speedup 1.0000x reference)
//
#include <hip/hip_runtime.h>

static constexpr int H  = 16;   // hidden channels
static constexpr int C  = 16;   // num classes

// ---------------- Layer 1: msg1 = W1[et, src]; atomic scatter-add into acc1[dst] ----
// 4 threads per edge, each handles 4 channels (one float4 of the 64B W1 row).
__global__ void k1_scatter(const int* __restrict__ srcv, const int* __restrict__ dstv,
                           const int* __restrict__ etv, const float* __restrict__ W1,
                           float* __restrict__ acc1, int E, int N) {
    int t = blockIdx.x * blockDim.x + threadIdx.x;
    if (t >= E * 4) return;
    int e = t >> 2;
    int g = t & 3;
    int s = srcv[e];
    int d = dstv[e];
    int r = etv[e];
    const float4 v = *(const float4*)(W1 + ((size_t)r * N + (size_t)s) * H + g * 4);
    float* o = acc1 + (size_t)d * H + g * 4;
    unsafeAtomicAdd(o + 0, v.x);
    unsafeAtomicAdd(o + 1, v.y);
    unsafeAtomicAdd(o + 2, v.z);
    unsafeAtomicAdd(o + 3, v.w);
}

// ---------------- h1 = relu(root1 + acc1 + bias1), vectorized float4 ----------------
__global__ void k2_fin1(const float* __restrict__ root1, const float* __restrict__ bias1,
                        const float* __restrict__ acc1, float* __restrict__ h1, int total4) {
    int i = blockIdx.x * blockDim.x + threadIdx.x;
    if (i >= total4) return;
    float4 rv = ((const float4*)root1)[i];
    float4 av = ((const float4*)acc1)[i];
    float4 bv = ((const float4*)bias1)[i & 3];   // H=16 -> 4 float4 chunks of bias
    float4 o;
    o.x = fmaxf(rv.x + av.x + bv.x, 0.0f);
    o.y = fmaxf(rv.y + av.y + bv.y, 0.0f);
    o.z = fmaxf(rv.z + av.z + bv.z, 0.0f);
    o.w = fmaxf(rv.w + av.w + bv.w, 0.0f);
    ((float4*)h1)[i] = o;
}

// ---------------- Layer 2: msg2 = h1[src] @ W2[et]; atomic scatter-add into out[dst] -
// One thread per edge: 16x16 matvec (512 FLOP), W2 (32KB total) is L1-resident.
__global__ void k3_scatter(const int* __restrict__ srcv, const int* __restrict__ dstv,
                           const int* __restrict__ etv, const float* __restrict__ h1,
                           const float* __restrict__ W2, float* __restrict__ out, int E) {
    int e = blockIdx.x * blockDim.x + threadIdx.x;
    if (e >= E) return;
    int s = srcv[e];
    int d = dstv[e];
    int r = etv[e];
    const float4* hr = (const float4*)(h1 + (size_t)s * H);
    float4 h0 = hr[0], h1v = hr[1], h2v = hr[2], h3v = hr[3];
    float hk[16] = {h0.x, h0.y, h0.z, h0.w, h1v.x, h1v.y, h1v.z, h1v.w,
                    h2v.x, h2v.y, h2v.z, h2v.w, h3v.x, h3v.y, h3v.z, h3v.w};
    const float4* w = (const float4*)(W2 + (size_t)r * H * C);
    float4 a0 = make_float4(0.f, 0.f, 0.f, 0.f);
    float4 a1 = a0, a2 = a0, a3 = a0;
#pragma unroll
    for (int k = 0; k < 16; ++k) {
        float hv = hk[k];
        float4 w0 = w[k * 4 + 0];
        float4 w1 = w[k * 4 + 1];
        float4 w2v = w[k * 4 + 2];
        float4 w3 = w[k * 4 + 3];
        a0.x += hv * w0.x;  a0.y += hv * w0.y;  a0.z += hv * w0.z;  a0.w += hv * w0.w;
        a1.x += hv * w1.x;  a1.y += hv * w1.y;  a1.z += hv * w1.z;  a1.w += hv * w1.w;
        a2.x += hv * w2v.x; a2.y += hv * w2v.y; a2.z += hv * w2v.z; a2.w += hv * w2v.w;
        a3.x += hv * w3.x;  a3.y += hv * w3.y;  a3.z += hv * w3.z;  a3.w += hv * w3.w;
    }
    float* o = out + (size_t)d * C;
    unsafeAtomicAdd(o + 0,  a0.x); unsafeAtomicAdd(o + 1,  a0.y);
    unsafeAtomicAdd(o + 2,  a0.z); unsafeAtomicAdd(o + 3,  a0.w);
    unsafeAtomicAdd(o + 4,  a1.x); unsafeAtomicAdd(o + 5,  a1.y);
    unsafeAtomicAdd(o + 6,  a1.z); unsafeAtomicAdd(o + 7,  a1.w);
    unsafeAtomicAdd(o + 8,  a2.x); unsafeAtomicAdd(o + 9,  a2.y);
    unsafeAtomicAdd(o + 10, a2.z); unsafeAtomicAdd(o + 11, a2.w);
    unsafeAtomicAdd(o + 12, a3.x); unsafeAtomicAdd(o + 13, a3.y);
    unsafeAtomicAdd(o + 14, a3.z); unsafeAtomicAdd(o + 15, a3.w);
}

// ---------------- h2 = h1 @ root2 + acc2 + bias2; row log_softmax --------------------
__global__ void k4_fin2(const float* __restrict__ h1, const float* __restrict__ root2,
                        const float* __restrict__ bias2, float* __restrict__ out, int N) {
    int n = blockIdx.x * blockDim.x + threadIdx.x;
    if (n >= N) return;
    const float* hr = h1 + (size_t)n * H;
    float h[16];
#pragma unroll
    for (int k = 0; k < 16; ++k) h[k] = hr[k];
    float* o = out + (size_t)n * C;
    float z[16];
#pragma unroll
    for (int c = 0; c < 16; ++c) {
        float acc = o[c] + bias2[c];
#pragma unroll
        for (int k = 0; k < 16; ++k) acc += h[k] * root2[k * C + c];
        z[c] = acc;
    }
    float m = z[0];
#pragma unroll
    for (int c = 1; c < 16; ++c) m = fmaxf(m, z[c]);
    float se = 0.f;
#pragma unroll
    for (int c = 0; c < 16; ++c) se += __expf(z[c] - m);
    float lse = m + __logf(se);
#pragma unroll
    for (int c = 0; c < 16; ++c) o[c] = z[c] - lse;
}

extern "C" void kernel_launch(void* const* d_in, const int* in_sizes, int n_in,
                              void* d_out, int out_size, void* d_ws, size_t ws_size,
                              hipStream_t stream) {
    const int*   edge_index = (const int*)d_in[0];
    const int*   edge_type  = (const int*)d_in[1];
    // d_in[2] = tensor_slice, unused (per-edge edge_type is enough)
    const float* W1    = (const float*)d_in[3];
    const float* root1 = (const float*)d_in[4];
    const float* bias1 = (const float*)d_in[5];
    const float* W2    = (const float*)d_in[6];
    const float* root2 = (const float*)d_in[7];
    const float* bias2 = (const float*)d_in[8];
    float* out = (float*)d_out;

    const int E = in_sizes[0] / 2;
    const int N = in_sizes[4] / H;          // root1 is N*H
    const int* srcv = edge_index;           // edge_index row 0
    const int* dstv = edge_index + E;       // edge_index row 1

    float* acc1 = (float*)d_ws;             // N*H floats
    float* h1   = acc1 + (size_t)N * H;     // N*H floats

    // Zero accumulators every call (d_out/d_ws are poisoned, not re-poisoned).
    hipMemsetAsync(acc1, 0, (size_t)N * H * sizeof(float), stream);
    hipMemsetAsync(out, 0, (size_t)out_size * sizeof(float), stream);

    const int B = 256;
    int t1 = E * 4;
    k1_scatter<<<(t1 + B - 1) / B, B, 0, stream>>>(srcv, dstv, edge_type, W1, acc1, E, N);
    int total4 = N * H / 4;
    k2_fin1<<<(total4 + B - 1) / B, B, 0, stream>>>(root1, bias1, acc1, h1, total4);
    k3_scatter<<<(E + B - 1) / B, B, 0, stream>>>(srcv, dstv, edge_type, h1, W2, out, E);
    k4_fin2<<<(N + B - 1) / B, B, 0, stream>>>(h1, root2, bias2, out, N);
}

// Round 2
// 216.377 us; speedup vs baseline: 7.6879x; 7.6879x over previous
//
#include <hip/hip_runtime.h>

static constexpr int H  = 16;   // hidden channels
static constexpr int C  = 16;   // num classes

// ---------------- Layer 1: msg1 = W1[et, src]; atomic scatter-add into acc1[dst] ----
// 16 threads per edge, one channel each: a single atomic instruction covers the
// full 64B output row (lanes 0-15 contiguous) -> max same-line merge at TCC.
__global__ void k1_scatter(const int* __restrict__ srcv, const int* __restrict__ dstv,
                           const int* __restrict__ etv, const float* __restrict__ W1,
                           float* __restrict__ acc1, int E, int N) {
    int t = blockIdx.x * blockDim.x + threadIdx.x;
    if (t >= E * 16) return;
    int e = t >> 4;
    int c = t & 15;
    int s = srcv[e];
    int d = dstv[e];
    int r = etv[e];
    float v = W1[((size_t)r * N + (size_t)s) * H + c];   // coalesced 64B per edge-group
    unsafeAtomicAdd(acc1 + (size_t)d * H + c, v);
}

// ---------------- h1 = relu(root1 + acc1 + bias1), vectorized float4 ----------------
__global__ void k2_fin1(const float* __restrict__ root1, const float* __restrict__ bias1,
                        const float* __restrict__ acc1, float* __restrict__ h1, int total4) {
    int i = blockIdx.x * blockDim.x + threadIdx.x;
    if (i >= total4) return;
    float4 rv = ((const float4*)root1)[i];
    float4 av = ((const float4*)acc1)[i];
    float4 bv = ((const float4*)bias1)[i & 3];   // H=16 -> 4 float4 chunks of bias
    float4 o;
    o.x = fmaxf(rv.x + av.x + bv.x, 0.0f);
    o.y = fmaxf(rv.y + av.y + bv.y, 0.0f);
    o.z = fmaxf(rv.z + av.z + bv.z, 0.0f);
    o.w = fmaxf(rv.w + av.w + bv.w, 0.0f);
    ((float4*)h1)[i] = o;
}

// ---------------- Layer 2: msg2 = h1[src] @ W2[et]; atomic scatter-add into out[dst] -
// 16 threads per edge, one output channel each: per-lane 16-FMA dot product
// (W2 is 32KB total -> L1-resident), then ONE atomic per lane so lanes 0-15
// cover the edge's full 64B output row in a single atomic instruction.
__global__ void k3_scatter(const int* __restrict__ srcv, const int* __restrict__ dstv,
                           const int* __restrict__ etv, const float* __restrict__ h1,
                           const float* __restrict__ W2, float* __restrict__ out, int E) {
    int t = blockIdx.x * blockDim.x + threadIdx.x;
    if (t >= E * 16) return;
    int e = t >> 4;
    int c = t & 15;
    int s = srcv[e];
    int d = dstv[e];
    int r = etv[e];
    const float4* hr = (const float4*)(h1 + (size_t)s * H);   // same addr across edge-group
    float4 h0 = hr[0], h1v = hr[1], h2v = hr[2], h3v = hr[3];
    const float* w = W2 + (size_t)r * H * C + c;              // column c, stride C
    float acc = 0.f;
    acc += h0.x * w[0 * C];  acc += h0.y * w[1 * C];
    acc += h0.z * w[2 * C];  acc += h0.w * w[3 * C];
    acc += h1v.x * w[4 * C]; acc += h1v.y * w[5 * C];
    acc += h1v.z * w[6 * C]; acc += h1v.w * w[7 * C];
    acc += h2v.x * w[8 * C]; acc += h2v.y * w[9 * C];
    acc += h2v.z * w[10 * C]; acc += h2v.w * w[11 * C];
    acc += h3v.x * w[12 * C]; acc += h3v.y * w[13 * C];
    acc += h3v.z * w[14 * C]; acc += h3v.w * w[15 * C];
    unsafeAtomicAdd(out + (size_t)d * C + c, acc);
}

// ---------------- h2 = h1 @ root2 + acc2 + bias2; row log_softmax --------------------
__global__ void k4_fin2(const float* __restrict__ h1, const float* __restrict__ root2,
                        const float* __restrict__ bias2, float* __restrict__ out, int N) {
    int n = blockIdx.x * blockDim.x + threadIdx.x;
    if (n >= N) return;
    const float* hr = h1 + (size_t)n * H;
    float h[16];
#pragma unroll
    for (int k = 0; k < 16; ++k) h[k] = hr[k];
    float* o = out + (size_t)n * C;
    float z[16];
#pragma unroll
    for (int c = 0; c < 16; ++c) {
        float acc = o[c] + bias2[c];
#pragma unroll
        for (int k = 0; k < 16; ++k) acc += h[k] * root2[k * C + c];
        z[c] = acc;
    }
    float m = z[0];
#pragma unroll
    for (int c = 1; c < 16; ++c) m = fmaxf(m, z[c]);
    float se = 0.f;
#pragma unroll
    for (int c = 0; c < 16; ++c) se += __expf(z[c] - m);
    float lse = m + __logf(se);
#pragma unroll
    for (int c = 0; c < 16; ++c) o[c] = z[c] - lse;
}

extern "C" void kernel_launch(void* const* d_in, const int* in_sizes, int n_in,
                              void* d_out, int out_size, void* d_ws, size_t ws_size,
                              hipStream_t stream) {
    const int*   edge_index = (const int*)d_in[0];
    const int*   edge_type  = (const int*)d_in[1];
    // d_in[2] = tensor_slice, unused (per-edge edge_type is enough)
    const float* W1    = (const float*)d_in[3];
    const float* root1 = (const float*)d_in[4];
    const float* bias1 = (const float*)d_in[5];
    const float* W2    = (const float*)d_in[6];
    const float* root2 = (const float*)d_in[7];
    const float* bias2 = (const float*)d_in[8];
    float* out = (float*)d_out;

    const int E = in_sizes[0] / 2;
    const int N = in_sizes[4] / H;          // root1 is N*H
    const int* srcv = edge_index;           // edge_index row 0
    const int* dstv = edge_index + E;       // edge_index row 1

    float* acc1 = (float*)d_ws;             // N*H floats
    float* h1   = acc1 + (size_t)N * H;     // N*H floats

    // Zero accumulators every call (d_out/d_ws are poisoned, not re-poisoned).
    hipMemsetAsync(acc1, 0, (size_t)N * H * sizeof(float), stream);
    hipMemsetAsync(out, 0, (size_t)out_size * sizeof(float), stream);

    const int B = 256;
    int t16 = E * 16;
    k1_scatter<<<(t16 + B - 1) / B, B, 0, stream>>>(srcv, dstv, edge_type, W1, acc1, E, N);
    int total4 = N * H / 4;
    k2_fin1<<<(total4 + B - 1) / B, B, 0, stream>>>(root1, bias1, acc1, h1, total4);
    k3_scatter<<<(t16 + B - 1) / B, B, 0, stream>>>(srcv, dstv, edge_type, h1, W2, out, E);
    k4_fin2<<<(N + B - 1) / B, B, 0, stream>>>(h1, root2, bias2, out, N);
}

// Round 3
// 197.475 us; speedup vs baseline: 8.4237x; 1.0957x over previous
//
#include <hip/hip_runtime.h>
#include <hip/hip_bf16.h>

static constexpr int H  = 16;   // hidden channels
static constexpr int C  = 16;   // num classes

typedef __attribute__((ext_vector_type(8))) short bf16x8;
typedef __attribute__((ext_vector_type(4))) float f32x4;

static __device__ inline unsigned short f2bf(float x) {
    __hip_bfloat16 b = __float2bfloat16(x);
    return *reinterpret_cast<unsigned short*>(&b);
}

// ---------------- Layer 1: msg1 = W1[et, src]; atomic scatter-add into acc1[dst] ----
// 16 threads per edge, one channel each: one atomic instruction covers the full
// 64B output row -> one L2 line-touch per edge (floor).
__global__ void k1_scatter(const int* __restrict__ srcv, const int* __restrict__ dstv,
                           const int* __restrict__ etv, const float* __restrict__ W1,
                           float* __restrict__ acc1, int E, int N) {
    int t = blockIdx.x * blockDim.x + threadIdx.x;
    if (t >= E * 16) return;
    int e = t >> 4;
    int c = t & 15;
    int s = srcv[e];
    int d = dstv[e];
    int r = etv[e];
    float v = W1[((size_t)r * N + (size_t)s) * H + c];
    unsafeAtomicAdd(acc1 + (size_t)d * H + c, v);
}

// ---------------- h1 = relu(root1 + acc1 + bias1); also write bf16 copy ------------
__global__ void k2_fin1(const float* __restrict__ root1, const float* __restrict__ bias1,
                        const float* __restrict__ acc1, float* __restrict__ h1,
                        unsigned int* __restrict__ h1bf /*as uint2 per float4*/, int total4) {
    int i = blockIdx.x * blockDim.x + threadIdx.x;
    if (i >= total4) return;
    float4 rv = ((const float4*)root1)[i];
    float4 av = ((const float4*)acc1)[i];
    float4 bv = ((const float4*)bias1)[i & 3];
    float4 o;
    o.x = fmaxf(rv.x + av.x + bv.x, 0.0f);
    o.y = fmaxf(rv.y + av.y + bv.y, 0.0f);
    o.z = fmaxf(rv.z + av.z + bv.z, 0.0f);
    o.w = fmaxf(rv.w + av.w + bv.w, 0.0f);
    ((float4*)h1)[i] = o;
    uint2 p;
    p.x = ((unsigned)f2bf(o.y) << 16) | f2bf(o.x);
    p.y = ((unsigned)f2bf(o.w) << 16) | f2bf(o.z);
    ((uint2*)h1bf)[i] = p;
}

// ---------------- prep: per-relation 16-edge chunk offsets (exclusive scan) --------
__global__ void k0_prep(const int* __restrict__ ts, int* __restrict__ chunk_off, int R) {
    if (blockIdx.x == 0 && threadIdx.x == 0) {
        int acc = 0;
        for (int r = 0; r < R; ++r) {
            chunk_off[r] = acc;
            int cnt = ts[2 * r + 1] - ts[2 * r];
            acc += (cnt + 15) >> 4;
        }
        chunk_off[R] = acc;
    }
}

// ---------------- prep: W2 -> bf16, transposed to [R][C][H] ------------------------
__global__ void k0_cast(const float* __restrict__ W2, unsigned short* __restrict__ w2t,
                        int total /* R*H*C */) {
    int i = blockIdx.x * blockDim.x + threadIdx.x;
    if (i >= total) return;
    int r = i >> 8;
    int kc = i & 255;
    int k = kc >> 4;
    int c = kc & 15;
    w2t[(r << 8) + (c << 4) + k] = f2bf(W2[i]);
}

// ---------------- Layer 2 via MFMA: one wave = 16 edges of ONE relation ------------
// D[16x16] = A(h1bf rows, gathered) x B(W2^T[r]) with K=32 (upper 16 zero-padded).
// A: lane row = l&15, k = (l>>4)*8+j.  B: lane col = l&15 from row-major [C][H].
// D: col = l&15, row = (l>>4)*4 + reg.
__global__ void k3_mfma(const int* __restrict__ srcv, const int* __restrict__ dstv,
                        const int* __restrict__ ts, const int* __restrict__ chunk_off,
                        const unsigned short* __restrict__ h1bf,
                        const unsigned short* __restrict__ w2t,
                        float* __restrict__ out, int R) {
    int w = (blockIdx.x * blockDim.x + threadIdx.x) >> 6;
    int l = threadIdx.x & 63;
    int total = chunk_off[R];
    if (w >= total) return;
    // largest r with chunk_off[r] <= w  (chunk_off ascending, R+1 entries)
    int lo = 0, hi = R;
    while (hi - lo > 1) {
        int mid = (lo + hi) >> 1;
        if (chunk_off[mid] <= w) lo = mid; else hi = mid;
    }
    int r = lo;
    int e0 = ts[2 * r] + ((w - chunk_off[r]) << 4);
    int eend = ts[2 * r + 1];
    int n_e = min(16, eend - e0);

    int rowA = l & 15;           // A-row (edge) and B-col (channel) are both l&15
    int kg = l >> 4;
    int eA = e0 + min(rowA, n_e - 1);   // clamp: garbage rows get skipped at atomic
    int s = srcv[eA];

    bf16x8 a = {0, 0, 0, 0, 0, 0, 0, 0};
    bf16x8 b = {0, 0, 0, 0, 0, 0, 0, 0};
    if (kg < 2) {               // k = kg*8 .. kg*8+7 covers real K=16; kg>=2 is zero-pad
        a = *(const bf16x8*)(h1bf + ((size_t)s << 4) + (kg << 3));
        b = *(const bf16x8*)(w2t + ((size_t)r << 8) + (rowA << 4) + (kg << 3));
    }
    f32x4 d = {0.f, 0.f, 0.f, 0.f};
    d = __builtin_amdgcn_mfma_f32_16x16x32_bf16(a, b, d, 0, 0, 0);

    int c = l & 15;
#pragma unroll
    for (int j = 0; j < 4; ++j) {
        int row = (kg << 2) + j;
        if (row < n_e) {
            int dd = dstv[e0 + row];
            unsafeAtomicAdd(out + ((size_t)dd << 4) + c, d[j]);
        }
    }
}

// ---------------- h2 = h1 @ root2 + acc2 + bias2; row log_softmax ------------------
__global__ void k4_fin2(const float* __restrict__ h1, const float* __restrict__ root2,
                        const float* __restrict__ bias2, float* __restrict__ out, int N) {
    int n = blockIdx.x * blockDim.x + threadIdx.x;
    if (n >= N) return;
    const float* hr = h1 + (size_t)n * H;
    float h[16];
#pragma unroll
    for (int k = 0; k < 16; ++k) h[k] = hr[k];
    float* o = out + (size_t)n * C;
    float z[16];
#pragma unroll
    for (int c = 0; c < 16; ++c) {
        float acc = o[c] + bias2[c];
#pragma unroll
        for (int k = 0; k < 16; ++k) acc += h[k] * root2[k * C + c];
        z[c] = acc;
    }
    float m = z[0];
#pragma unroll
    for (int c = 1; c < 16; ++c) m = fmaxf(m, z[c]);
    float se = 0.f;
#pragma unroll
    for (int c = 0; c < 16; ++c) se += __expf(z[c] - m);
    float lse = m + __logf(se);
#pragma unroll
    for (int c = 0; c < 16; ++c) o[c] = z[c] - lse;
}

extern "C" void kernel_launch(void* const* d_in, const int* in_sizes, int n_in,
                              void* d_out, int out_size, void* d_ws, size_t ws_size,
                              hipStream_t stream) {
    const int*   edge_index   = (const int*)d_in[0];
    const int*   edge_type    = (const int*)d_in[1];
    const int*   tensor_slice = (const int*)d_in[2];
    const float* W1    = (const float*)d_in[3];
    const float* root1 = (const float*)d_in[4];
    const float* bias1 = (const float*)d_in[5];
    const float* W2    = (const float*)d_in[6];
    const float* root2 = (const float*)d_in[7];
    const float* bias2 = (const float*)d_in[8];
    float* out = (float*)d_out;

    const int E = in_sizes[0] / 2;
    const int N = in_sizes[4] / H;           // root1 is N*H
    const int R = in_sizes[2] / 2;           // tensor_slice is [R][2]
    const int* srcv = edge_index;
    const int* dstv = edge_index + E;

    // ws layout (floats): acc1 [N*H] | h1 [N*H] | h1bf [N*H/2] | w2t [R*H*C/2] | chunk_off
    float* acc1 = (float*)d_ws;
    float* h1   = acc1 + (size_t)N * H;
    unsigned short* h1bf = (unsigned short*)(h1 + (size_t)N * H);
    unsigned short* w2t  = h1bf + (size_t)N * H;
    int* chunk_off = (int*)(w2t + (size_t)R * H * C);

    hipMemsetAsync(acc1, 0, (size_t)N * H * sizeof(float), stream);
    hipMemsetAsync(out, 0, (size_t)out_size * sizeof(float), stream);

    const int B = 256;
    // prep (cheap, overlappable)
    k0_prep<<<1, 64, 0, stream>>>(tensor_slice, chunk_off, R);
    k0_cast<<<(R * H * C + B - 1) / B, B, 0, stream>>>(W2, w2t, R * H * C);
    // layer 1
    int t16 = E * 16;
    k1_scatter<<<(t16 + B - 1) / B, B, 0, stream>>>(srcv, dstv, edge_type, W1, acc1, E, N);
    int total4 = N * H / 4;
    k2_fin1<<<(total4 + B - 1) / B, B, 0, stream>>>(root1, bias1, acc1, h1,
                                                    (unsigned int*)h1bf, total4);
    // layer 2: upper bound on 16-edge chunks = ceil(E/16) + R (waves self-exit past total)
    long long waves_ub = (long long)((E + 15) / 16) + R;
    long long thr = waves_ub * 64;
    k3_mfma<<<(int)((thr + B - 1) / B), B, 0, stream>>>(srcv, dstv, tensor_slice, chunk_off,
                                                        h1bf, w2t, out, R);
    k4_fin2<<<(N + B - 1) / B, B, 0, stream>>>(h1, root2, bias2, out, N);
}

// Round 4
// 197.040 us; speedup vs baseline: 8.4423x; 1.0022x over previous
//
#include <hip/hip_runtime.h>
#include <hip/hip_bf16.h>

static constexpr int H  = 16;   // hidden channels
static constexpr int C  = 16;   // num classes

typedef __attribute__((ext_vector_type(8))) short bf16x8;
typedef __attribute__((ext_vector_type(4))) float f32x4;

static __device__ inline unsigned short f2bf(float x) {
    __hip_bfloat16 b = __float2bfloat16(x);
    return *reinterpret_cast<unsigned short*>(&b);
}

// ---------------- Layer 1: msg1 = W1[et, src]; atomic scatter-add into acc1[dst] ----
// 16 threads x 4 edges per thread-group: batch the index loads, the 4 random W1
// gathers, and the 4 atomic instructions so each wave has 16 gather lines and
// 4 atomic instrs in flight (latency hiding), at unchanged traffic.
__global__ void k1_scatter(const int* __restrict__ srcv, const int* __restrict__ dstv,
                           const int* __restrict__ etv, const float* __restrict__ W1,
                           float* __restrict__ acc1, int E, int N) {
    int t = blockIdx.x * blockDim.x + threadIdx.x;
    int g = t >> 4;            // group of 4 edges
    int c = t & 15;
    int e0 = g << 2;
    if (e0 >= E) return;
    int n = min(4, E - e0);
    int s[4], d[4], r[4];
    float v[4];
#pragma unroll
    for (int i = 0; i < 4; ++i) {
        int e = e0 + ((i < n) ? i : 0);
        s[i] = srcv[e]; d[i] = dstv[e]; r[i] = etv[e];
    }
#pragma unroll
    for (int i = 0; i < 4; ++i)
        v[i] = W1[((size_t)r[i] * N + (size_t)s[i]) * H + c];
#pragma unroll
    for (int i = 0; i < 4; ++i)
        if (i < n) unsafeAtomicAdd(acc1 + ((size_t)d[i] << 4) + c, v[i]);
}

// ---------------- h1 = relu(root1 + acc1 + bias1); also write bf16 copy ------------
__global__ void k2_fin1(const float* __restrict__ root1, const float* __restrict__ bias1,
                        const float* __restrict__ acc1, float* __restrict__ h1,
                        unsigned int* __restrict__ h1bf /*as uint2 per float4*/, int total4) {
    int i = blockIdx.x * blockDim.x + threadIdx.x;
    if (i >= total4) return;
    float4 rv = ((const float4*)root1)[i];
    float4 av = ((const float4*)acc1)[i];
    float4 bv = ((const float4*)bias1)[i & 3];
    float4 o;
    o.x = fmaxf(rv.x + av.x + bv.x, 0.0f);
    o.y = fmaxf(rv.y + av.y + bv.y, 0.0f);
    o.z = fmaxf(rv.z + av.z + bv.z, 0.0f);
    o.w = fmaxf(rv.w + av.w + bv.w, 0.0f);
    ((float4*)h1)[i] = o;
    uint2 p;
    p.x = ((unsigned)f2bf(o.y) << 16) | f2bf(o.x);
    p.y = ((unsigned)f2bf(o.w) << 16) | f2bf(o.z);
    ((uint2*)h1bf)[i] = p;
}

// ---------------- prep: per-relation 16-edge chunk offsets (exclusive scan) --------
__global__ void k0_prep(const int* __restrict__ ts, int* __restrict__ chunk_off, int R) {
    if (blockIdx.x == 0 && threadIdx.x == 0) {
        int acc = 0;
        for (int r = 0; r < R; ++r) {
            chunk_off[r] = acc;
            int cnt = ts[2 * r + 1] - ts[2 * r];
            acc += (cnt + 15) >> 4;
        }
        chunk_off[R] = acc;
    }
}

// ---------------- prep: W2 -> bf16, transposed to [R][C][H] ------------------------
__global__ void k0_cast(const float* __restrict__ W2, unsigned short* __restrict__ w2t,
                        int total /* R*H*C */) {
    int i = blockIdx.x * blockDim.x + threadIdx.x;
    if (i >= total) return;
    int r = i >> 8;
    int kc = i & 255;
    int k = kc >> 4;
    int c = kc & 15;
    w2t[(r << 8) + (c << 4) + k] = f2bf(W2[i]);
}

// ---------------- Layer 2 via MFMA: one wave = 16 edges of ONE relation ------------
// D[16x16] = A(h1bf rows, gathered) x B(W2^T[r]) with K=32 (upper 16 zero-padded).
// A: lane row = l&15, k = (l>>4)*8+j.  B: lane col = l&15 from row-major [C][H].
// D: col = l&15, row = (l>>4)*4 + reg.
__global__ void k3_mfma(const int* __restrict__ srcv, const int* __restrict__ dstv,
                        const int* __restrict__ ts, const int* __restrict__ chunk_off,
                        const unsigned short* __restrict__ h1bf,
                        const unsigned short* __restrict__ w2t,
                        float* __restrict__ out, int R) {
    int w = (blockIdx.x * blockDim.x + threadIdx.x) >> 6;
    int l = threadIdx.x & 63;
    int total = chunk_off[R];
    if (w >= total) return;
    // largest r with chunk_off[r] <= w  (chunk_off ascending, R+1 entries)
    int lo = 0, hi = R;
    while (hi - lo > 1) {
        int mid = (lo + hi) >> 1;
        if (chunk_off[mid] <= w) lo = mid; else hi = mid;
    }
    int r = lo;
    int e0 = ts[2 * r] + ((w - chunk_off[r]) << 4);
    int eend = ts[2 * r + 1];
    int n_e = min(16, eend - e0);

    int rowA = l & 15;           // A-row (edge) and B-col (channel) are both l&15
    int kg = l >> 4;
    int eA = e0 + min(rowA, n_e - 1);   // clamp: garbage rows get skipped at atomic
    int s = srcv[eA];

    bf16x8 a = {0, 0, 0, 0, 0, 0, 0, 0};
    bf16x8 b = {0, 0, 0, 0, 0, 0, 0, 0};
    if (kg < 2) {               // k = kg*8 .. kg*8+7 covers real K=16; kg>=2 is zero-pad
        a = *(const bf16x8*)(h1bf + ((size_t)s << 4) + (kg << 3));
        b = *(const bf16x8*)(w2t + ((size_t)r << 8) + (rowA << 4) + (kg << 3));
    }
    f32x4 d = {0.f, 0.f, 0.f, 0.f};
    d = __builtin_amdgcn_mfma_f32_16x16x32_bf16(a, b, d, 0, 0, 0);

    int c = l & 15;
#pragma unroll
    for (int j = 0; j < 4; ++j) {
        int row = (kg << 2) + j;
        if (row < n_e) {
            int dd = dstv[e0 + row];
            unsafeAtomicAdd(out + ((size_t)dd << 4) + c, d[j]);
        }
    }
}

// ---------------- h2 = h1 @ root2 + acc2 + bias2; row log_softmax ------------------
__global__ void k4_fin2(const float* __restrict__ h1, const float* __restrict__ root2,
                        const float* __restrict__ bias2, float* __restrict__ out, int N) {
    int n = blockIdx.x * blockDim.x + threadIdx.x;
    if (n >= N) return;
    const float* hr = h1 + (size_t)n * H;
    float h[16];
#pragma unroll
    for (int k = 0; k < 16; ++k) h[k] = hr[k];
    float* o = out + (size_t)n * C;
    float z[16];
#pragma unroll
    for (int c = 0; c < 16; ++c) {
        float acc = o[c] + bias2[c];
#pragma unroll
        for (int k = 0; k < 16; ++k) acc += h[k] * root2[k * C + c];
        z[c] = acc;
    }
    float m = z[0];
#pragma unroll
    for (int c = 1; c < 16; ++c) m = fmaxf(m, z[c]);
    float se = 0.f;
#pragma unroll
    for (int c = 0; c < 16; ++c) se += __expf(z[c] - m);
    float lse = m + __logf(se);
#pragma unroll
    for (int c = 0; c < 16; ++c) o[c] = z[c] - lse;
}

extern "C" void kernel_launch(void* const* d_in, const int* in_sizes, int n_in,
                              void* d_out, int out_size, void* d_ws, size_t ws_size,
                              hipStream_t stream) {
    const int*   edge_index   = (const int*)d_in[0];
    const int*   edge_type    = (const int*)d_in[1];
    const int*   tensor_slice = (const int*)d_in[2];
    const float* W1    = (const float*)d_in[3];
    const float* root1 = (const float*)d_in[4];
    const float* bias1 = (const float*)d_in[5];
    const float* W2    = (const float*)d_in[6];
    const float* root2 = (const float*)d_in[7];
    const float* bias2 = (const float*)d_in[8];
    float* out = (float*)d_out;

    const int E = in_sizes[0] / 2;
    const int N = in_sizes[4] / H;           // root1 is N*H
    const int R = in_sizes[2] / 2;           // tensor_slice is [R][2]
    const int* srcv = edge_index;
    const int* dstv = edge_index + E;

    // ws layout (floats): acc1 [N*H] | h1 [N*H] | h1bf [N*H/2] | w2t [R*H*C/2] | chunk_off
    float* acc1 = (float*)d_ws;
    float* h1   = acc1 + (size_t)N * H;
    unsigned short* h1bf = (unsigned short*)(h1 + (size_t)N * H);
    unsigned short* w2t  = h1bf + (size_t)N * H;
    int* chunk_off = (int*)(w2t + (size_t)R * H * C);

    hipMemsetAsync(acc1, 0, (size_t)N * H * sizeof(float), stream);
    hipMemsetAsync(out, 0, (size_t)out_size * sizeof(float), stream);

    const int B = 256;
    // prep (cheap, overlappable)
    k0_prep<<<1, 64, 0, stream>>>(tensor_slice, chunk_off, R);
    k0_cast<<<(R * H * C + B - 1) / B, B, 0, stream>>>(W2, w2t, R * H * C);
    // layer 1: 4 edges per thread-of-16
    long long g1 = ((long long)E + 3) / 4;       // edge groups
    long long t1 = g1 * 16;
    k1_scatter<<<(int)((t1 + B - 1) / B), B, 0, stream>>>(srcv, dstv, edge_type, W1, acc1, E, N);
    int total4 = N * H / 4;
    k2_fin1<<<(total4 + B - 1) / B, B, 0, stream>>>(root1, bias1, acc1, h1,
                                                    (unsigned int*)h1bf, total4);
    // layer 2: upper bound on 16-edge chunks = ceil(E/16) + R (waves self-exit past total)
    long long waves_ub = (long long)((E + 15) / 16) + R;
    long long thr = waves_ub * 64;
    k3_mfma<<<(int)((thr + B - 1) / B), B, 0, stream>>>(srcv, dstv, tensor_slice, chunk_off,
                                                        h1bf, w2t, out, R);
    k4_fin2<<<(N + B - 1) / B, B, 0, stream>>>(h1, root2, bias2, out, N);
}